// Round 1
// baseline (2057.243 us; speedup 1.0000x reference)
//
#include <hip/hip_runtime.h>
#include <math.h>

#define NPATHS 4096
#define PLEN 7
#define DIM 128
#define G4 512            // 4*HIDDEN
#define PB 32             // paths per block
#define BLOCKS_PER_MP 128 // 4096/32
#define KTILE 16
#define WT_PAD 514        // padded (even) row length of transposed W tile

__device__ __forceinline__ float sigmoidf_(float x) {
    return 1.0f / (1.0f + __expf(-x));
}
__device__ __forceinline__ float tanhf_(float x) {
    // tanh(x) = 2*sigmoid(2x) - 1
    return 2.0f / (1.0f + __expf(-2.0f * x)) - 1.0f;
}

// ---------------------------------------------------------------------------
// Kernel A: per-path LSTM, fused gather + gates + state update.
// Grid: 512 blocks (mp = bid>>7, 128 blocks per metapath), 256 threads.
// Each block: 32 paths. Thread (pg = t>>6, jg = t&63) computes gates for
// 8 paths (pg*8..pg*8+7) x 2 hidden units (j2 = jg*2, j2+1) x 4 gate types.
// Writes per-block partial sums of final h to ws[bid][0..127].
// ---------------------------------------------------------------------------
__global__ __launch_bounds__(256, 2)
void lstm_paths(const int* __restrict__ id0, const int* __restrict__ id1,
                const int* __restrict__ id2, const int* __restrict__ id3,
                const float* __restrict__ emb,
                const float* __restrict__ W_ih, const float* __restrict__ W_hh,
                const float* __restrict__ b_ih, const float* __restrict__ b_hh,
                float* __restrict__ ws)
{
    __shared__ float x_lds[PB][DIM];
    __shared__ float h_lds[PB][DIM];
    __shared__ float w_t[KTILE][WT_PAD];   // transposed W tile: w_t[kk][gate]

    const int t   = threadIdx.x;
    const int bid = blockIdx.x;
    const int mp  = bid >> 7;
    const int blk = bid & 127;
    const int p0  = blk * PB;
    const int* __restrict__ ids = (mp == 0) ? id0 : (mp == 1) ? id1 : (mp == 2) ? id2 : id3;

    const int jg = t & 63;
    const int pg = t >> 6;
    const int j2 = jg * 2;

    // combined bias for (i,f,g,o) at hidden units j2, j2+1
    float2 bias[4];
#pragma unroll
    for (int gi = 0; gi < 4; ++gi) {
        int g = gi * DIM + j2;
        float2 bi = *(const float2*)&b_ih[g];
        float2 bh = *(const float2*)&b_hh[g];
        bias[gi] = make_float2(bi.x + bh.x, bi.y + bh.y);
    }

    // cell state for 8 paths x 2 hidden units
    float2 cst[8];
#pragma unroll
    for (int p = 0; p < 8; ++p) cst[p] = make_float2(0.f, 0.f);

#pragma unroll 1
    for (int step = 0; step < PLEN; ++step) {
        // ---- stage x tile: 32 rows x 128 floats (gather) ----
        {
            const int col4  = t & 31;   // float4 column
            const int rbase = t >> 5;   // 0..7
#pragma unroll
            for (int rr = 0; rr < 4; ++rr) {
                int row  = rbase + rr * 8;
                int node = ids[(p0 + row) * PLEN + step];
                float4 v = *(const float4*)&emb[(size_t)node * DIM + col4 * 4];
                *(float4*)&x_lds[row][col4 * 4] = v;
            }
        }

        float2 acc[8][4];
#pragma unroll
        for (int p = 0; p < 8; ++p)
#pragma unroll
            for (int gi = 0; gi < 4; ++gi) acc[p][gi] = make_float2(0.f, 0.f);

        const int ntiles = (step == 0) ? 8 : 16;   // step 0: h == 0, skip W_hh half
#pragma unroll 1
        for (int tile = 0; tile < ntiles; ++tile) {
            __syncthreads();  // w_t reuse + x/h ready
            // ---- stage transposed W tile: w_t[kk][g] = W[g][k0+kk] ----
            {
                const float* __restrict__ Wsrc = (tile < 8) ? W_ih : W_hh;
                const int k0 = (tile < 8) ? tile * KTILE : (tile - 8) * KTILE;
#pragma unroll
                for (int r = 0; r < 8; ++r) {
                    int idx = r * 256 + t;     // 0..2047
                    int g   = idx >> 2;        // 0..511
                    int q   = idx & 3;         // 0..3
                    float4 v = *(const float4*)&Wsrc[g * DIM + k0 + q * 4];
                    w_t[q * 4 + 0][g] = v.x;
                    w_t[q * 4 + 1][g] = v.y;
                    w_t[q * 4 + 2][g] = v.z;
                    w_t[q * 4 + 3][g] = v.w;
                }
            }
            __syncthreads();

            const float* __restrict__ src = (tile < 8) ? &x_lds[0][0] : &h_lds[0][0];
            const int koff = (tile < 8) ? tile * KTILE : (tile - 8) * KTILE;
#pragma unroll
            for (int kk = 0; kk < KTILE; kk += 2) {
                float2 xv[8];
#pragma unroll
                for (int p = 0; p < 8; ++p)
                    xv[p] = *(const float2*)&src[(pg * 8 + p) * DIM + koff + kk];
                float2 wa[4], wb[4];
#pragma unroll
                for (int gi = 0; gi < 4; ++gi) {
                    wa[gi] = *(const float2*)&w_t[kk][gi * DIM + j2];
                    wb[gi] = *(const float2*)&w_t[kk + 1][gi * DIM + j2];
                }
#pragma unroll
                for (int p = 0; p < 8; ++p)
#pragma unroll
                    for (int gi = 0; gi < 4; ++gi) {
                        acc[p][gi].x += xv[p].x * wa[gi].x + xv[p].y * wb[gi].x;
                        acc[p][gi].y += xv[p].x * wa[gi].y + xv[p].y * wb[gi].y;
                    }
            }
        }
        __syncthreads();  // all reads of h_lds done before overwrite

        // ---- elementwise gate math + state update, write h to LDS ----
#pragma unroll
        for (int p = 0; p < 8; ++p) {
            float2 iv, fv, gv, ov;
            iv.x = sigmoidf_(acc[p][0].x + bias[0].x);
            iv.y = sigmoidf_(acc[p][0].y + bias[0].y);
            fv.x = sigmoidf_(acc[p][1].x + bias[1].x);
            fv.y = sigmoidf_(acc[p][1].y + bias[1].y);
            gv.x = tanhf_(acc[p][2].x + bias[2].x);
            gv.y = tanhf_(acc[p][2].y + bias[2].y);
            ov.x = sigmoidf_(acc[p][3].x + bias[3].x);
            ov.y = sigmoidf_(acc[p][3].y + bias[3].y);
            cst[p].x = fv.x * cst[p].x + iv.x * gv.x;
            cst[p].y = fv.y * cst[p].y + iv.y * gv.y;
            float2 hv;
            hv.x = ov.x * tanhf_(cst[p].x);
            hv.y = ov.y * tanhf_(cst[p].y);
            *(float2*)&h_lds[pg * 8 + p][j2] = hv;
        }
        __syncthreads();  // h ready for next step (and x_lds free to overwrite)
    }

    // ---- per-block partial sum over the 32 paths ----
    if (t < DIM) {
        float s = 0.f;
#pragma unroll
        for (int p = 0; p < PB; ++p) s += h_lds[p][t];
        ws[bid * DIM + t] = s;
    }
}

// ---------------------------------------------------------------------------
// Kernel B: deterministic reduce: mean over 4096 paths, maxpool over 4 reps,
// linear(128->1) + sigmoid. 1 block, 512 threads (t>>7 = mp, t&127 = j).
// ---------------------------------------------------------------------------
__global__ __launch_bounds__(512)
void finalize(const float* __restrict__ ws,
              const float* __restrict__ W_lin, const float* __restrict__ b_lin,
              float* __restrict__ out)
{
    __shared__ float s_lds[4 * DIM];
    __shared__ float red[2];

    const int t  = threadIdx.x;
    const int mp = t >> 7;
    const int j  = t & 127;

    float s = 0.f;
#pragma unroll 8
    for (int b = 0; b < BLOCKS_PER_MP; ++b)
        s += ws[(mp * BLOCKS_PER_MP + b) * DIM + j];
    s_lds[mp * DIM + j] = s;
    __syncthreads();

    if (t < DIM) {
        float m = -1e30f;
#pragma unroll
        for (int k = 0; k < 4; ++k) m = fmaxf(m, s_lds[k * DIM + t]);
        m *= (1.0f / (float)NPATHS);
        float v = m * W_lin[t];
        v += __shfl_xor(v, 1);
        v += __shfl_xor(v, 2);
        v += __shfl_xor(v, 4);
        v += __shfl_xor(v, 8);
        v += __shfl_xor(v, 16);
        v += __shfl_xor(v, 32);
        if ((t & 63) == 0) red[t >> 6] = v;
    }
    __syncthreads();
    if (t == 0) {
        float tot = red[0] + red[1] + b_lin[0];
        out[0] = 1.0f / (1.0f + __expf(-tot));
    }
}

extern "C" void kernel_launch(void* const* d_in, const int* in_sizes, int n_in,
                              void* d_out, int out_size, void* d_ws, size_t ws_size,
                              hipStream_t stream) {
    const int*   id0   = (const int*)d_in[0];
    const int*   id1   = (const int*)d_in[1];
    const int*   id2   = (const int*)d_in[2];
    const int*   id3   = (const int*)d_in[3];
    const float* emb   = (const float*)d_in[4];
    const float* W_ih  = (const float*)d_in[5];
    const float* W_hh  = (const float*)d_in[6];
    const float* b_ih  = (const float*)d_in[7];
    const float* b_hh  = (const float*)d_in[8];
    const float* W_lin = (const float*)d_in[9];
    const float* b_lin = (const float*)d_in[10];

    float* ws  = (float*)d_ws;   // 512 * 128 floats = 256 KB partial sums
    float* out = (float*)d_out;

    hipLaunchKernelGGL(lstm_paths, dim3(4 * BLOCKS_PER_MP), dim3(256), 0, stream,
                       id0, id1, id2, id3, emb, W_ih, W_hh, b_ih, b_hh, ws);
    hipLaunchKernelGGL(finalize, dim3(1), dim3(512), 0, stream,
                       ws, W_lin, b_lin, out);
}

// Round 2
// 83.511 us; speedup vs baseline: 24.6345x; 24.6345x over previous
//
#include <hip/hip_runtime.h>
#include <math.h>

#define NPATHS 4096
#define PLEN 7
#define DIM 128
#define PB 64              // paths per block
#define BLOCKS_PER_MP 64   // 4096 / 64
#define XPAD 136           // padded bf16 row stride (+8 kills 16-way bank conflicts)

typedef __attribute__((ext_vector_type(8))) short short8;
typedef __attribute__((ext_vector_type(4))) float f32x4;

__device__ __forceinline__ unsigned short f2bf(float f) {
    unsigned u = __float_as_uint(f);
    u += 0x7fffu + ((u >> 16) & 1u);     // RNE
    return (unsigned short)(u >> 16);
}
__device__ __forceinline__ float sigmoidf_(float x) { return 1.0f / (1.0f + __expf(-x)); }
__device__ __forceinline__ float tanhf_(float x)    { return 2.0f / (1.0f + __expf(-2.0f * x)) - 1.0f; }

// ---------------------------------------------------------------------------
// Fused gather + LSTM on matrix cores.
// Grid: 256 blocks (mp = bid>>6), 512 threads = 8 waves.
// Block handles 64 paths. Wave w owns hidden-column tile jt=w (16 cols) for
// all 4 gates; W_ih/W_hh B-fragments live in registers (32 x short8 = 128 VGPR).
// x and h tiles live in LDS as bf16 (double-buffered). c state in VGPRs.
// MFMA: D(16 paths x 16 gatecols) = A(paths x k) * B(k x gatecols).
//   A-frag: lane reads row (l&15), k = kk*32 + (l>>4)*8 .. +8  (ds_read_b128)
//   B-frag: lane holds W[col][k], col = gi*128 + w*16 + (l&15), same k slice
//   D:      col = l&15, row(path) = (l>>4)*4 + reg
// ---------------------------------------------------------------------------
__global__ __launch_bounds__(512, 2)
void lstm_fused(const int* __restrict__ id0, const int* __restrict__ id1,
                const int* __restrict__ id2, const int* __restrict__ id3,
                const float* __restrict__ emb,
                const float* __restrict__ W_ih, const float* __restrict__ W_hh,
                const float* __restrict__ b_ih, const float* __restrict__ b_hh,
                float* __restrict__ ws)
{
    __shared__ __align__(16) unsigned short x_buf[2][PB][XPAD];
    __shared__ __align__(16) unsigned short h_buf[2][PB][XPAD];

    const int t    = threadIdx.x;
    const int w    = t >> 6;          // wave id == hidden col tile jt
    const int lane = t & 63;
    const int l15  = lane & 15;
    const int lg   = lane >> 4;       // 0..3
    const int bid  = blockIdx.x;
    const int mp   = bid >> 6;
    const int p0   = (bid & 63) * PB;
    const int* __restrict__ ids = (mp == 0) ? id0 : (mp == 1) ? id1 : (mp == 2) ? id2 : id3;

    // ---- one-time: W fragments (bf16) + combined bias into registers ----
    short8 wih[4][4], whh[4][4];
    float  biasv[4];
    const float4* wih4 = (const float4*)W_ih;
    const float4* whh4 = (const float4*)W_hh;
#pragma unroll
    for (int gi = 0; gi < 4; ++gi) {
        const int col = gi * DIM + w * 16 + l15;     // W row index (gate output)
        biasv[gi] = b_ih[col] + b_hh[col];
#pragma unroll
        for (int kk = 0; kk < 4; ++kk) {
            const int q = col * 32 + kk * 8 + lg * 2;  // float4 index; k0 = kk*32+lg*8
            float4 a = wih4[q], b = wih4[q + 1];
            short8 f;
            f[0] = (short)f2bf(a.x); f[1] = (short)f2bf(a.y);
            f[2] = (short)f2bf(a.z); f[3] = (short)f2bf(a.w);
            f[4] = (short)f2bf(b.x); f[5] = (short)f2bf(b.y);
            f[6] = (short)f2bf(b.z); f[7] = (short)f2bf(b.w);
            wih[gi][kk] = f;
            a = whh4[q]; b = whh4[q + 1];
            f[0] = (short)f2bf(a.x); f[1] = (short)f2bf(a.y);
            f[2] = (short)f2bf(a.z); f[3] = (short)f2bf(a.w);
            f[4] = (short)f2bf(b.x); f[5] = (short)f2bf(b.y);
            f[6] = (short)f2bf(b.z); f[7] = (short)f2bf(b.w);
            whh[gi][kk] = f;
        }
    }

    // ---- prologue: gather x for step 0 ----
    const int grow = t >> 3;          // 0..63 path row
    const int gqb  = t & 7;           // float4 quad base
    {
        const int node = ids[(p0 + grow) * PLEN + 0];
        const float4* e4 = (const float4*)(emb + (size_t)node * DIM);
#pragma unroll
        for (int rr = 0; rr < 4; ++rr) {
            float4 v = e4[gqb + 8 * rr];
            unsigned lo = (unsigned)f2bf(v.x) | ((unsigned)f2bf(v.y) << 16);
            unsigned hi = (unsigned)f2bf(v.z) | ((unsigned)f2bf(v.w) << 16);
            uint2 pk; pk.x = lo; pk.y = hi;
            *(uint2*)&x_buf[0][grow][(gqb + 8 * rr) * 4] = pk;
        }
    }
    __syncthreads();

    f32x4 cst[4];
#pragma unroll
    for (int m = 0; m < 4; ++m) { cst[m][0] = 0.f; cst[m][1] = 0.f; cst[m][2] = 0.f; cst[m][3] = 0.f; }
    float hsum = 0.f;

#pragma unroll 1
    for (int s = 0; s < PLEN; ++s) {
        const int cur = s & 1, nxt = cur ^ 1;

        // prefetch next step's x rows into registers (completes under compute)
        float4 pf[4];
        const bool has = (s + 1 < PLEN);
        if (has) {
            const int node = ids[(p0 + grow) * PLEN + s + 1];
            const float4* e4 = (const float4*)(emb + (size_t)node * DIM);
#pragma unroll
            for (int rr = 0; rr < 4; ++rr) pf[rr] = e4[gqb + 8 * rr];
        }

        // ---- compute: one 16-path m-tile at a time ----
#pragma unroll
        for (int m = 0; m < 4; ++m) {
            const int arow = m * 16 + l15;
            const int acol = lg * 8;
            f32x4 acc[4];
#pragma unroll
            for (int gi = 0; gi < 4; ++gi) {
                acc[gi][0] = biasv[gi]; acc[gi][1] = biasv[gi];
                acc[gi][2] = biasv[gi]; acc[gi][3] = biasv[gi];
            }
#pragma unroll
            for (int kk = 0; kk < 4; ++kk) {
                short8 a = *(const short8*)&x_buf[cur][arow][kk * 32 + acol];
#pragma unroll
                for (int gi = 0; gi < 4; ++gi)
                    acc[gi] = __builtin_amdgcn_mfma_f32_16x16x32_bf16(a, wih[gi][kk], acc[gi], 0, 0, 0);
            }
            if (s > 0) {
#pragma unroll
                for (int kk = 0; kk < 4; ++kk) {
                    short8 a = *(const short8*)&h_buf[cur][arow][kk * 32 + acol];
#pragma unroll
                    for (int gi = 0; gi < 4; ++gi)
                        acc[gi] = __builtin_amdgcn_mfma_f32_16x16x32_bf16(a, whh[gi][kk], acc[gi], 0, 0, 0);
                }
            }
            // elementwise LSTM cell (all in registers; D-layout path = m*16+lg*4+r)
#pragma unroll
            for (int r = 0; r < 4; ++r) {
                float iv = sigmoidf_(acc[0][r]);
                float fv = sigmoidf_(acc[1][r]);
                float gv = tanhf_(acc[2][r]);
                float ov = sigmoidf_(acc[3][r]);
                float c  = (s == 0) ? iv * gv : fv * cst[m][r] + iv * gv;
                cst[m][r] = c;
                float hv = ov * tanhf_(c);
                if (s == PLEN - 1) hsum += hv;
                h_buf[nxt][m * 16 + lg * 4 + r][w * 16 + l15] = f2bf(hv);
            }
        }

        // write prefetched x to the other buffer (readers of it finished at s-1's sync)
        if (has) {
#pragma unroll
            for (int rr = 0; rr < 4; ++rr) {
                unsigned lo = (unsigned)f2bf(pf[rr].x) | ((unsigned)f2bf(pf[rr].y) << 16);
                unsigned hi = (unsigned)f2bf(pf[rr].z) | ((unsigned)f2bf(pf[rr].w) << 16);
                uint2 pk; pk.x = lo; pk.y = hi;
                *(uint2*)&x_buf[nxt][grow][(gqb + 8 * rr) * 4] = pk;
            }
        }
        __syncthreads();
    }

    // ---- per-block partial sum of final h over 64 paths (fp32, in-register) ----
    hsum += __shfl_xor(hsum, 16);
    hsum += __shfl_xor(hsum, 32);
    if (lg == 0) ws[bid * DIM + w * 16 + l15] = hsum;
}

// ---------------------------------------------------------------------------
// Finalize: mean over 4096 paths, maxpool over 4 metapaths, linear + sigmoid.
// ---------------------------------------------------------------------------
__global__ __launch_bounds__(512)
void finalize(const float* __restrict__ ws,
              const float* __restrict__ W_lin, const float* __restrict__ b_lin,
              float* __restrict__ out)
{
    __shared__ float s_lds[4 * DIM];
    __shared__ float red[2];

    const int t  = threadIdx.x;
    const int mp = t >> 7;
    const int j  = t & 127;

    float s = 0.f;
#pragma unroll 8
    for (int b = 0; b < BLOCKS_PER_MP; ++b)
        s += ws[(mp * BLOCKS_PER_MP + b) * DIM + j];
    s_lds[mp * DIM + j] = s;
    __syncthreads();

    if (t < DIM) {
        float m = -1e30f;
#pragma unroll
        for (int k = 0; k < 4; ++k) m = fmaxf(m, s_lds[k * DIM + t]);
        m *= (1.0f / (float)NPATHS);
        float v = m * W_lin[t];
        v += __shfl_xor(v, 1);
        v += __shfl_xor(v, 2);
        v += __shfl_xor(v, 4);
        v += __shfl_xor(v, 8);
        v += __shfl_xor(v, 16);
        v += __shfl_xor(v, 32);
        if ((t & 63) == 0) red[t >> 6] = v;
    }
    __syncthreads();
    if (t == 0) {
        float tot = red[0] + red[1] + b_lin[0];
        out[0] = 1.0f / (1.0f + __expf(-tot));
    }
}

extern "C" void kernel_launch(void* const* d_in, const int* in_sizes, int n_in,
                              void* d_out, int out_size, void* d_ws, size_t ws_size,
                              hipStream_t stream) {
    const int*   id0   = (const int*)d_in[0];
    const int*   id1   = (const int*)d_in[1];
    const int*   id2   = (const int*)d_in[2];
    const int*   id3   = (const int*)d_in[3];
    const float* emb   = (const float*)d_in[4];
    const float* W_ih  = (const float*)d_in[5];
    const float* W_hh  = (const float*)d_in[6];
    const float* b_ih  = (const float*)d_in[7];
    const float* b_hh  = (const float*)d_in[8];
    const float* W_lin = (const float*)d_in[9];
    const float* b_lin = (const float*)d_in[10];

    float* ws  = (float*)d_ws;   // 256 * 128 floats = 128 KB partial sums
    float* out = (float*)d_out;

    hipLaunchKernelGGL(lstm_fused, dim3(4 * BLOCKS_PER_MP), dim3(512), 0, stream,
                       id0, id1, id2, id3, emb, W_ih, W_hh, b_ih, b_hh, ws);
    hipLaunchKernelGGL(finalize, dim3(1), dim3(512), 0, stream,
                       ws, W_lin, b_lin, out);
}